// Round 1
// baseline (365.022 us; speedup 1.0000x reference)
//
#include <hip/hip_runtime.h>

// ---------------------------------------------------------------------------
// AlignmentForce: chain-COM periodic alignment + restraint force projection.
//
// ws float layout (first 128 floats zeroed every launch):
//   [  0.. 47] poc_sum[MAXC][3]   (segment sums of positions[poc_indices])
//   [ 48.. 95] ref_sum[MAXC][3]   (segment sums of ref_poc)
//   [ 96..111] cnt[MAXC]
//   [112..114] origin_sum[3]
//   [116..118] F_sum[3]
//   [119..121] T_sum[3]
//   [128..175] best_t[MAXC][3]    (written by k_best_t, not zeroed-needed)
// ---------------------------------------------------------------------------

#define MAXC 16
#define W_POC 0
#define W_REF 48
#define W_CNT 96
#define W_OSUM 112
#define W_FSUM 116
#define W_TSUM 119
#define W_BT 128
#define W_ZERO_FLOATS 128

__device__ inline float waveSum(float v) {
#pragma unroll
  for (int off = 32; off > 0; off >>= 1) v += __shfl_down(v, off, 64);
  return v;
}

// K1: per-chain sums over pocket atoms. NOTE: reference (faithfully buggy)
// indexes GLOBAL positions with poc_indices (rec-space indices) for the COM.
__global__ void k_chain_sums(const float* __restrict__ pos,
                             const float* __restrict__ ref_poc,
                             const int* __restrict__ poc_idx,
                             const int* __restrict__ poc_cid,
                             const int* __restrict__ ncp,
                             int P, float* __restrict__ ws) {
  const int C = ncp[0];
  __shared__ float acc[4 * MAXC * 7];  // one replica per wave (256 thr = 4 waves)
  const int wid = threadIdx.x >> 6;
  float* wacc = &acc[wid * MAXC * 7];
  for (int t = threadIdx.x; t < 4 * MAXC * 7; t += blockDim.x) acc[t] = 0.f;
  __syncthreads();
  for (int j = blockIdx.x * blockDim.x + threadIdx.x; j < P;
       j += gridDim.x * blockDim.x) {
    int i = poc_idx[j];
    int c = poc_cid[j];
    float px = pos[3 * i + 0], py = pos[3 * i + 1], pz = pos[3 * i + 2];
    float rx = ref_poc[3 * j + 0], ry = ref_poc[3 * j + 1], rz = ref_poc[3 * j + 2];
    float* a = &wacc[c * 7];
    atomicAdd(&a[0], px); atomicAdd(&a[1], py); atomicAdd(&a[2], pz);
    atomicAdd(&a[3], rx); atomicAdd(&a[4], ry); atomicAdd(&a[5], rz);
    atomicAdd(&a[6], 1.f);
  }
  __syncthreads();
  for (int t = threadIdx.x; t < C * 7; t += blockDim.x) {
    int c = t / 7, q = t % 7;
    float v = acc[t] + acc[MAXC * 7 + t] + acc[2 * MAXC * 7 + t] +
              acc[3 * MAXC * 7 + t];
    if (q < 3)      atomicAdd(&ws[W_POC + c * 3 + q], v);
    else if (q < 6) atomicAdd(&ws[W_REF + c * 3 + (q - 3)], v);
    else            atomicAdd(&ws[W_CNT + c], v);
  }
}

// K2: per-chain best periodic translation (faithful to reference order:
// subtract s3*row2, then s2*row1, then s1*row0; rintf == round-half-even).
__global__ void k_best_t(const float* __restrict__ box,
                         const int* __restrict__ ncp,
                         float* __restrict__ ws) {
  int c = threadIdx.x;
  int C = ncp[0];
  if (c >= C) return;
  float cnt = ws[W_CNT + c];
  float pcx = ws[W_POC + c * 3 + 0] / cnt;
  float pcy = ws[W_POC + c * 3 + 1] / cnt;
  float pcz = ws[W_POC + c * 3 + 2] / cnt;
  float rcx = ws[W_REF + c * 3 + 0] / cnt;
  float rcy = ws[W_REF + c * 3 + 1] / cnt;
  float rcz = ws[W_REF + c * 3 + 2] / cnt;
  float dx = rcx - pcx, dy = rcy - pcy, dz = rcz - pcz;
  float inv0 = 1.f / box[0], inv1 = 1.f / box[4], inv2 = 1.f / box[8];
  float s3 = rintf(dz * inv2);
  dx -= s3 * box[6]; dy -= s3 * box[7]; dz -= s3 * box[8];
  float s2 = rintf(dy * inv1);
  dx -= s2 * box[3]; dy -= s2 * box[4]; dz -= s2 * box[5];
  float s1 = rintf(dx * inv0);
  ws[W_BT + c * 3 + 0] = s1 * box[0] + s2 * box[3] + s3 * box[6];
  ws[W_BT + c * 3 + 1] = s1 * box[1] + s2 * box[4] + s3 * box[7];
  ws[W_BT + c * 3 + 2] = s1 * box[2] + s2 * box[5] + s3 * box[8];
}

// K3: origin_sum = sum over rec atoms of (positions[rec_idx] + best_t[chain]).
__global__ void k_origin_sum(const float* __restrict__ pos,
                             const int* __restrict__ rec_idx,
                             const int* __restrict__ cid,
                             const int* __restrict__ ncp,
                             int R, float* __restrict__ ws) {
  __shared__ float bt[MAXC * 3];
  __shared__ float bacc[3];
  int C3 = ncp[0] * 3;
  if (threadIdx.x < 3) bacc[threadIdx.x] = 0.f;
  for (int t = threadIdx.x; t < C3; t += blockDim.x) bt[t] = ws[W_BT + t];
  __syncthreads();
  float sx = 0.f, sy = 0.f, sz = 0.f;
  for (int r = blockIdx.x * blockDim.x + threadIdx.x; r < R;
       r += gridDim.x * blockDim.x) {
    int i = rec_idx[r], c = cid[r];
    sx += pos[3 * i + 0] + bt[3 * c + 0];
    sy += pos[3 * i + 1] + bt[3 * c + 1];
    sz += pos[3 * i + 2] + bt[3 * c + 2];
  }
  sx = waveSum(sx); sy = waveSum(sy); sz = waveSum(sz);
  if ((threadIdx.x & 63) == 0) {
    atomicAdd(&bacc[0], sx); atomicAdd(&bacc[1], sy); atomicAdd(&bacc[2], sz);
  }
  __syncthreads();
  if (threadIdx.x < 3) atomicAdd(&ws[W_OSUM + threadIdx.x], bacc[threadIdx.x]);
}

// K4: F_sum and torque_sum over pocket rows only (F is zero elsewhere).
__global__ void k_pocket_sums(const float* __restrict__ pos,
                              const float* __restrict__ ref_poc,
                              const int* __restrict__ rec_idx,
                              const int* __restrict__ poc_idx,
                              const int* __restrict__ poc_cid,
                              const int* __restrict__ ncp,
                              const float* __restrict__ kp,
                              int P, float Rf, float* __restrict__ ws) {
  __shared__ float bt[MAXC * 3];
  __shared__ float bacc[6];
  int C3 = ncp[0] * 3;
  float kk = kp[0];
  float ox = ws[W_OSUM + 0] / Rf;
  float oy = ws[W_OSUM + 1] / Rf;
  float oz = ws[W_OSUM + 2] / Rf;
  if (threadIdx.x < 6) bacc[threadIdx.x] = 0.f;
  for (int t = threadIdx.x; t < C3; t += blockDim.x) bt[t] = ws[W_BT + t];
  __syncthreads();
  float fx = 0.f, fy = 0.f, fz = 0.f, tx = 0.f, ty = 0.f, tz = 0.f;
  for (int j = blockIdx.x * blockDim.x + threadIdx.x; j < P;
       j += gridDim.x * blockDim.x) {
    int i = poc_idx[j];
    int c = poc_cid[j];
    int ri = rec_idx[i];
    float rpx = pos[3 * ri + 0] + bt[3 * c + 0];
    float rpy = pos[3 * ri + 1] + bt[3 * c + 1];
    float rpz = pos[3 * ri + 2] + bt[3 * c + 2];
    float fvx = -2.f * kk * (rpx - ref_poc[3 * j + 0]);
    float fvy = -2.f * kk * (rpy - ref_poc[3 * j + 1]);
    float fvz = -2.f * kk * (rpz - ref_poc[3 * j + 2]);
    float cx = rpx - ox, cy = rpy - oy, cz = rpz - oz;
    fx += fvx; fy += fvy; fz += fvz;
    tx += cy * fvz - cz * fvy;
    ty += cz * fvx - cx * fvz;
    tz += cx * fvy - cy * fvx;
  }
  fx = waveSum(fx); fy = waveSum(fy); fz = waveSum(fz);
  tx = waveSum(tx); ty = waveSum(ty); tz = waveSum(tz);
  if ((threadIdx.x & 63) == 0) {
    atomicAdd(&bacc[0], fx); atomicAdd(&bacc[1], fy); atomicAdd(&bacc[2], fz);
    atomicAdd(&bacc[3], tx); atomicAdd(&bacc[4], ty); atomicAdd(&bacc[5], tz);
  }
  __syncthreads();
  // W_FSUM..W_FSUM+2 then W_TSUM..W_TSUM+2 are contiguous (116..121)
  if (threadIdx.x < 6) atomicAdd(&ws[W_FSUM + threadIdx.x], bacc[threadIdx.x]);
}

// K5: F_final[rec_idx[r]] = F_mean + cross(torque_mean, c)/r_sq
__global__ void k_final(const float* __restrict__ pos,
                        const int* __restrict__ rec_idx,
                        const int* __restrict__ cid,
                        const int* __restrict__ ncp,
                        int R, float Rf,
                        const float* __restrict__ ws,
                        float* __restrict__ out) {
  __shared__ float bt[MAXC * 3];
  int C3 = ncp[0] * 3;
  for (int t = threadIdx.x; t < C3; t += blockDim.x) bt[t] = ws[W_BT + t];
  float ox = ws[W_OSUM + 0] / Rf, oy = ws[W_OSUM + 1] / Rf, oz = ws[W_OSUM + 2] / Rf;
  float fmx = ws[W_FSUM + 0] / Rf, fmy = ws[W_FSUM + 1] / Rf, fmz = ws[W_FSUM + 2] / Rf;
  float tmx = ws[W_TSUM + 0] / Rf, tmy = ws[W_TSUM + 1] / Rf, tmz = ws[W_TSUM + 2] / Rf;
  __syncthreads();
  for (int r = blockIdx.x * blockDim.x + threadIdx.x; r < R;
       r += gridDim.x * blockDim.x) {
    int i = rec_idx[r], c = cid[r];
    float cx = pos[3 * i + 0] + bt[3 * c + 0] - ox;
    float cy = pos[3 * i + 1] + bt[3 * c + 1] - oy;
    float cz = pos[3 * i + 2] + bt[3 * c + 2] - oz;
    float rsq = cx * cx + cy * cy + cz * cz;
    float inv = 1.f / rsq;
    float frx = (tmy * cz - tmz * cy) * inv;  // cross(torque_mean, c)
    float fry = (tmz * cx - tmx * cz) * inv;
    float frz = (tmx * cy - tmy * cx) * inv;
    out[1 + 3 * i + 0] = fmx + frx;
    out[1 + 3 * i + 1] = fmy + fry;
    out[1 + 3 * i + 2] = fmz + frz;
  }
}

extern "C" void kernel_launch(void* const* d_in, const int* in_sizes, int n_in,
                              void* d_out, int out_size, void* d_ws, size_t ws_size,
                              hipStream_t stream) {
  const float* pos     = (const float*)d_in[0];
  const float* box     = (const float*)d_in[1];
  const float* ref_poc = (const float*)d_in[2];
  const float* kp      = (const float*)d_in[3];
  const int* rec_idx   = (const int*)d_in[4];
  const int* poc_idx   = (const int*)d_in[5];
  const int* cid       = (const int*)d_in[6];
  const int* poc_cid   = (const int*)d_in[7];
  const int* ncp       = (const int*)d_in[8];
  float* out = (float*)d_out;
  float* ws  = (float*)d_ws;

  const int R = in_sizes[4];
  const int P = in_sizes[5];
  const float Rf = (float)R;

  // zero accumulators + entire output (harness re-poisons both every call;
  // out[0] is the scalar energy = 0.0, non-receptor atoms must be 0)
  hipMemsetAsync(d_ws, 0, W_ZERO_FLOATS * sizeof(float), stream);
  hipMemsetAsync(d_out, 0, (size_t)out_size * sizeof(float), stream);

  const int blk = 256;
  int gP = (P + blk - 1) / blk; if (gP > 1024) gP = 1024;
  int gR = (R + blk - 1) / blk; if (gR > 2048) gR = 2048;

  k_chain_sums<<<gP, blk, 0, stream>>>(pos, ref_poc, poc_idx, poc_cid, ncp, P, ws);
  k_best_t<<<1, 64, 0, stream>>>(box, ncp, ws);
  k_origin_sum<<<gR, blk, 0, stream>>>(pos, rec_idx, cid, ncp, R, ws);
  k_pocket_sums<<<gP, blk, 0, stream>>>(pos, ref_poc, rec_idx, poc_idx, poc_cid,
                                        ncp, kp, P, Rf, ws);
  k_final<<<gR, blk, 0, stream>>>(pos, rec_idx, cid, ncp, R, Rf, ws, out);
}